// Round 4
// baseline (4976.001 us; speedup 1.0000x reference)
//
#include <hip/hip_runtime.h>

#define H 64
#define T_STEPS 2048

typedef _Float16 f16x8 __attribute__((ext_vector_type(8)));
typedef float    f32x4 __attribute__((ext_vector_type(4)));

__device__ __forceinline__ float sig_f(float x) {
    return 1.0f / (1.0f + __expf(-x));
}
__device__ __forceinline__ float tanh_f(float x) {
    return 2.0f / (1.0f + __expf(-2.0f * x)) - 1.0f;
}

// load 8 consecutive f32 -> f16x8 (setup only)
__device__ __forceinline__ f16x8 ldcvt8(const float* __restrict__ p) {
    float4 a = ((const float4*)p)[0];
    float4 c = ((const float4*)p)[1];
    f16x8 r;
    r[0]=(_Float16)a.x; r[1]=(_Float16)a.y; r[2]=(_Float16)a.z; r[3]=(_Float16)a.w;
    r[4]=(_Float16)c.x; r[5]=(_Float16)c.y; r[6]=(_Float16)c.z; r[7]=(_Float16)c.w;
    return r;
}

#define MFMA(a, b, c) __builtin_amdgcn_mfma_f32_16x16x32_f16((a), (b), (c), 0, 0, 0)

// R17: FUSED D-FRAGMENT CELL UPDATE — ONE BARRIER, NO gbuf.
// R16 post-mortem: correct MFMA/AGPR structure (1855us, MfmaUtil 30%)
// but 1 block/CU (grid=256=CUs, 1 seq each) means step time == serial
// critical path; R16's path had 2 barriers + a gbuf LDS round-trip
// purely to move the D-frag to dedicated act waves.
// R17: D-frag lane (l&15==0, kg=l>>4) of wave w ALREADY holds all 4
// gates (regs r=0..3) of cell ci=4w+kg for each layer -> do the cell
// update there (cst0/1/2 live in those lanes), ds_write_b16 the three
// h values straight to S, single barrier per step.
// MFMA chains split into 2+2 accumulators (latency 2 MFMA + 1 add,
// not 4 MFMA). Layer pipeline unchanged: L0 t=p, L1 t=p-1, L2 t=p-2,
// all reading slot (p+1)&1, writing slot p&1.
__global__ __launch_bounds__(1024, 4)
void lstm3_r17(const float* __restrict__ x,
               const float* __restrict__ Wih0, const float* __restrict__ Whh0,
               const float* __restrict__ bih0, const float* __restrict__ bhh0,
               const float* __restrict__ Wih1, const float* __restrict__ Whh1,
               const float* __restrict__ bih1, const float* __restrict__ bhh1,
               const float* __restrict__ Wih2, const float* __restrict__ Whh2,
               const float* __restrict__ bih2, const float* __restrict__ bhh2,
               const float* __restrict__ Wout, const float* __restrict__ bout,
               float* __restrict__ out)
{
    __shared__ __align__(16) float xs[T_STEPS * 2];   // 16 KB input seq (f32)
    // S: 2 slots x 384 halves. Rows 0-63 h0, 64-127 h1, 128-191 h2;
    // rows 192-383 permanent zeros (inactive-lane B reads).
    __shared__ __align__(16) _Float16 S[2][384];
    __shared__ __align__(16) float h2f[H];

    const int tid = threadIdx.x;
    const int b   = blockIdx.x;
    const int w   = tid >> 6;          // wave 0..15 = M-tile index
    const int l   = tid & 63;
    const int lj  = l & 15;            // A row-in-tile / D col
    const int kg  = l >> 4;            // k-group / D row-quad
    const int ci  = 4 * w + kg;        // cell owned by D lanes (lj==0)

    // ---- stage x[b,:,:]: one float4 per thread ----
    ((float4*)xs)[tid] = ((const float4*)(x + (size_t)b * T_STEPS * 2))[tid];

    // ---- A-fragments: permuted row' = 16w + lj <-> cell=4w+(lj>>2), gate=lj&3
    const int cellA = 4 * w + (lj >> 2);
    const int gateA = lj & 3;
    const int wrow  = gateA * H + cellA;   // row of the 256-row gate matrix
    const int kc    = kg * 8;              // k offset within a 64-col block

    f16x8 A00 = ldcvt8(Whh0 + wrow * H + kc);        // L0 <- h0 lo
    f16x8 A01 = ldcvt8(Whh0 + wrow * H + 32 + kc);   // L0 <- h0 hi
    f16x8 A10 = ldcvt8(Wih1 + wrow * H + kc);        // L1 <- h0 lo
    f16x8 A11 = ldcvt8(Wih1 + wrow * H + 32 + kc);   // L1 <- h0 hi
    f16x8 A12 = ldcvt8(Whh1 + wrow * H + kc);        // L1 <- h1 lo
    f16x8 A13 = ldcvt8(Whh1 + wrow * H + 32 + kc);   // L1 <- h1 hi
    f16x8 A20 = ldcvt8(Wih2 + wrow * H + kc);        // L2 <- h1 lo
    f16x8 A21 = ldcvt8(Wih2 + wrow * H + 32 + kc);   // L2 <- h1 hi
    f16x8 A22 = ldcvt8(Whh2 + wrow * H + kc);        // L2 <- h2 lo
    f16x8 A23 = ldcvt8(Whh2 + wrow * H + 32 + kc);   // L2 <- h2 hi
    // park in AGPRs once; MFMA consumes them there (no per-step copies)
    asm volatile("" : "+a"(A00), "+a"(A01), "+a"(A10), "+a"(A11));
    asm volatile("" : "+a"(A12), "+a"(A13), "+a"(A20), "+a"(A21));
    asm volatile("" : "+a"(A22), "+a"(A23));

    // ---- D-lane cell constants (meaningful on lj==0 lanes; computed on
    // all lanes to stay branch-free). 12 biases + 8 x-weights + 3 csts.
    float b0v[4], b1v[4], b2v[4], wxv[8];
#pragma unroll
    for (int g = 0; g < 4; ++g) {
        b0v[g] = bih0[g * H + ci] + bhh0[g * H + ci];
        b1v[g] = bih1[g * H + ci] + bhh1[g * H + ci];
        b2v[g] = bih2[g * H + ci] + bhh2[g * H + ci];
        wxv[2 * g]     = Wih0[(g * H + ci) * 2];
        wxv[2 * g + 1] = Wih0[(g * H + ci) * 2 + 1];
    }
    float cst0 = 0.f, cst1 = 0.f, cst2 = 0.f;

    // ---- zero S (both slots incl. zero pad) ----
    if (tid < 384) ((float*)S)[tid] = 0.f;
    __syncthreads();

    // B-frag byte offset within a slot: active lanes (lj==0) read their
    // k-group; inactive lanes read the zero pad.
    const char* Sb  = (const char*)S;
    const int  bofs = (lj == 0) ? (kg * 16) : 384;
    const f32x4 z = {0.f, 0.f, 0.f, 0.f};

#pragma unroll 1
    for (int p = 0; p < T_STEPS + 2; ++p) {
        const bool on0 = (p < T_STEPS);
        const bool on1 = (p >= 1) && (p <= T_STEPS);
        const bool on2 = (p >= 2);

        const int so = ((p + 1) & 1) * 768;        // read-slot byte offset
        const char* Bp = Sb + (bofs + so);
        f16x8 b0 = *(const f16x8*)(Bp + 0);        // S rows   0- 31 (h0 lo)
        f16x8 b1 = *(const f16x8*)(Bp + 64);       // S rows  32- 63 (h0 hi)
        f16x8 b2 = *(const f16x8*)(Bp + 128);      // S rows  64- 95 (h1 lo)
        f16x8 b3 = *(const f16x8*)(Bp + 192);      // S rows  96-127 (h1 hi)
        f16x8 b4 = *(const f16x8*)(Bp + 256);      // S rows 128-159 (h2 lo)
        f16x8 b5 = *(const f16x8*)(Bp + 320);      // S rows 160-191 (h2 hi)

        // x_t (uniform broadcast; issued early, consumed after MFMAs)
        const int px = on0 ? p : 0;
        float2 xt = *(const float2*)&xs[2 * px];

        // split accumulators: latency = 2 dependent MFMA + 1 vector add
        f32x4 g0, g1, g2;
        if (on0) { g0 = MFMA(A00, b0, z);  g0 = MFMA(A01, b1, g0); }
        if (on1) {
            f32x4 ga = MFMA(A10, b0, z);  ga = MFMA(A11, b1, ga);
            f32x4 gb = MFMA(A12, b2, z);  gb = MFMA(A13, b3, gb);
            g1 = ga + gb;
        }
        if (on2) {
            f32x4 ga = MFMA(A20, b2, z);  ga = MFMA(A21, b3, ga);
            f32x4 gb = MFMA(A22, b4, z);  gb = MFMA(A23, b5, gb);
            g2 = ga + gb;
        }

        // fused cell update on D lanes (col 0 holders); reg r = gate r
        if (lj == 0) {
            _Float16* Sw = S[p & 1];
            if (on0) {
                float pi = g0[0] + b0v[0] + wxv[0] * xt.x + wxv[1] * xt.y;
                float pf = g0[1] + b0v[1] + wxv[2] * xt.x + wxv[3] * xt.y;
                float pg = g0[2] + b0v[2] + wxv[4] * xt.x + wxv[5] * xt.y;
                float po = g0[3] + b0v[3] + wxv[6] * xt.x + wxv[7] * xt.y;
                float i_ = sig_f(pi), f_ = sig_f(pf);
                float g_ = tanh_f(pg), o_ = sig_f(po);
                cst0 = f_ * cst0 + i_ * g_;
                Sw[ci] = (_Float16)(o_ * tanh_f(cst0));
            }
            if (on1) {
                float pi = g1[0] + b1v[0], pf = g1[1] + b1v[1];
                float pg = g1[2] + b1v[2], po = g1[3] + b1v[3];
                float i_ = sig_f(pi), f_ = sig_f(pf);
                float g_ = tanh_f(pg), o_ = sig_f(po);
                cst1 = f_ * cst1 + i_ * g_;
                Sw[H + ci] = (_Float16)(o_ * tanh_f(cst1));
            }
            if (on2) {
                float pi = g2[0] + b2v[0], pf = g2[1] + b2v[1];
                float pg = g2[2] + b2v[2], po = g2[3] + b2v[3];
                float i_ = sig_f(pi), f_ = sig_f(pf);
                float g_ = tanh_f(pg), o_ = sig_f(po);
                cst2 = f_ * cst2 + i_ * g_;
                float hh = o_ * tanh_f(cst2);
                Sw[2 * H + ci] = (_Float16)hh;
                if (p == T_STEPS + 1) h2f[ci] = hh;   // final h2 (f32)
            }
        }
        __syncthreads();
    }

    // ---- fused projection: out[b,:] = h2_last @ Wout^T + bout ----
    if (tid < 11) {
        float acc = bout[tid];
#pragma unroll
        for (int jj = 0; jj < H; ++jj)
            acc += Wout[tid * H + jj] * h2f[jj];
        out[b * 11 + tid] = acc;
    }
}

extern "C" void kernel_launch(void* const* d_in, const int* in_sizes, int n_in,
                              void* d_out, int out_size, void* d_ws, size_t ws_size,
                              hipStream_t stream) {
    const float* x    = (const float*)d_in[0];
    const float* Wih0 = (const float*)d_in[1];
    const float* Whh0 = (const float*)d_in[2];
    const float* bih0 = (const float*)d_in[3];
    const float* bhh0 = (const float*)d_in[4];
    const float* Wih1 = (const float*)d_in[5];
    const float* Whh1 = (const float*)d_in[6];
    const float* bih1 = (const float*)d_in[7];
    const float* bhh1 = (const float*)d_in[8];
    const float* Wih2 = (const float*)d_in[9];
    const float* Whh2 = (const float*)d_in[10];
    const float* bih2 = (const float*)d_in[11];
    const float* bhh2 = (const float*)d_in[12];
    const float* Wout = (const float*)d_in[13];
    const float* bout = (const float*)d_in[14];
    float* out = (float*)d_out;

    lstm3_r17<<<256, 1024, 0, stream>>>(x,
        Wih0, Whh0, bih0, bhh0,
        Wih1, Whh1, bih1, bhh1,
        Wih2, Whh2, bih2, bhh2,
        Wout, bout, out);
}

// Round 5
// 2702.270 us; speedup vs baseline: 1.8414x; 1.8414x over previous
//
#include <hip/hip_runtime.h>

#define H 64
#define T_STEPS 2048

typedef _Float16 f16x8 __attribute__((ext_vector_type(8)));
typedef float    f32x4 __attribute__((ext_vector_type(4)));

__device__ __forceinline__ float sig_f(float x) {
    return 1.0f / (1.0f + __expf(-x));
}
__device__ __forceinline__ float tanh_f(float x) {
    return 2.0f / (1.0f + __expf(-2.0f * x)) - 1.0f;
}

// load 8 consecutive f32 -> f16x8 (setup only)
__device__ __forceinline__ f16x8 ldcvt8(const float* __restrict__ p) {
    float4 a = ((const float4*)p)[0];
    float4 c = ((const float4*)p)[1];
    f16x8 r;
    r[0]=(_Float16)a.x; r[1]=(_Float16)a.y; r[2]=(_Float16)a.z; r[3]=(_Float16)a.w;
    r[4]=(_Float16)c.x; r[5]=(_Float16)c.y; r[6]=(_Float16)c.z; r[7]=(_Float16)c.w;
    return r;
}

#define MFMA(a, b, c) __builtin_amdgcn_mfma_f32_16x16x32_f16((a), (b), (c), 0, 0, 0)

// R18: INTRA-WAVE ACT + SINGLE BARRIER.
// R17 lesson: act duplicated across 16 waves -> VALU pipe (1344 cyc/SIMD)
// became the bottleneck. R16 lesson: MFMA floor = 160 MFMA x 4.85 cyc =
// 776 cyc/step; everything else (2 barriers, gbuf round-trip, serial act
// phase) must hide under it.
// R18: wave w's D-lanes (l=16kg) hold gates of cells 4w+kg for ALL 3
// layers = 12 distinct (cell,layer) pairs per wave. Redistribute
// intra-wave via 12 __shfl to lanes 0-11 (lane t: layer t>>2, cell
// 4w+(t&3)) -> each wave does 12 updates, 1/lane, no duplication, no
// gbuf, no second barrier. Act (~110 cyc/wave issue, 4 waves/SIMD = 440)
// hides under the 776-cyc MFMA pipe (separate pipes). Bias + L0 x-term
// fold into the MFMA C-operand. One barrier/phase; slot p&1 written,
// slot (p+1)&1 read (race-free with single barrier).
// Pipeline unchanged: L0 t=p, L1 t=p-1, L2 t=p-2.
__global__ __launch_bounds__(1024, 4)
void lstm3_r18(const float* __restrict__ x,
               const float* __restrict__ Wih0, const float* __restrict__ Whh0,
               const float* __restrict__ bih0, const float* __restrict__ bhh0,
               const float* __restrict__ Wih1, const float* __restrict__ Whh1,
               const float* __restrict__ bih1, const float* __restrict__ bhh1,
               const float* __restrict__ Wih2, const float* __restrict__ Whh2,
               const float* __restrict__ bih2, const float* __restrict__ bhh2,
               const float* __restrict__ Wout, const float* __restrict__ bout,
               float* __restrict__ out)
{
    __shared__ __align__(16) float xs[T_STEPS * 2];   // 16 KB input seq (f32)
    // S: 2 slots x 384 halves. Rows 0-63 h0, 64-127 h1, 128-191 h2;
    // rows 192-383 permanent zeros (inactive-lane B reads).
    __shared__ __align__(16) _Float16 S[2][384];
    __shared__ __align__(16) float h2f[H];

    const int tid = threadIdx.x;
    const int b   = blockIdx.x;
    const int w   = tid >> 6;          // wave 0..15 = M-tile index
    const int l   = tid & 63;
    const int lj  = l & 15;            // A row-in-tile / D col
    const int kg  = l >> 4;            // k-group / D row-quad

    // ---- stage x[b,:,:]: one float4 per thread ----
    ((float4*)xs)[tid] = ((const float4*)(x + (size_t)b * T_STEPS * 2))[tid];

    // ---- A-fragments: permuted row' = 16w + lj <-> cell=4w+(lj>>2), gate=lj&3
    const int cellA = 4 * w + (lj >> 2);
    const int gateA = lj & 3;
    const int wrow  = gateA * H + cellA;   // row of the 256-row gate matrix
    const int kc    = kg * 8;              // k offset within a 64-col block

    f16x8 A00 = ldcvt8(Whh0 + wrow * H + kc);        // L0 <- h0 lo
    f16x8 A01 = ldcvt8(Whh0 + wrow * H + 32 + kc);   // L0 <- h0 hi
    f16x8 A10 = ldcvt8(Wih1 + wrow * H + kc);        // L1 <- h0 lo
    f16x8 A11 = ldcvt8(Wih1 + wrow * H + 32 + kc);   // L1 <- h0 hi
    f16x8 A12 = ldcvt8(Whh1 + wrow * H + kc);        // L1 <- h1 lo
    f16x8 A13 = ldcvt8(Whh1 + wrow * H + 32 + kc);   // L1 <- h1 hi
    f16x8 A20 = ldcvt8(Wih2 + wrow * H + kc);        // L2 <- h1 lo
    f16x8 A21 = ldcvt8(Wih2 + wrow * H + 32 + kc);   // L2 <- h1 hi
    f16x8 A22 = ldcvt8(Whh2 + wrow * H + kc);        // L2 <- h2 lo
    f16x8 A23 = ldcvt8(Whh2 + wrow * H + 32 + kc);   // L2 <- h2 hi
    // park in AGPRs once; MFMA consumes them there (no per-step copies)
    asm volatile("" : "+a"(A00), "+a"(A01), "+a"(A10), "+a"(A11));
    asm volatile("" : "+a"(A12), "+a"(A13), "+a"(A20), "+a"(A21));
    asm volatile("" : "+a"(A22), "+a"(A23));

    // ---- C-operand bias fragments: lane covers D rows kg*4+r ->
    // gate r of cell cd, any col (cols>=1 discarded).
    const int cd = 4 * w + kg;
    f32x4 cb0, cb1, cb2;
    float wxv[8];
#pragma unroll
    for (int r = 0; r < 4; ++r) {
        cb0[r] = bih0[r * H + cd] + bhh0[r * H + cd];
        cb1[r] = bih1[r * H + cd] + bhh1[r * H + cd];
        cb2[r] = bih2[r * H + cd] + bhh2[r * H + cd];
        wxv[2 * r]     = Wih0[(r * H + cd) * 2];
        wxv[2 * r + 1] = Wih0[(r * H + cd) * 2 + 1];
    }

    // ---- act-lane mapping (lanes 0..11): layer lam, cell ca ----
    const int lam  = l >> 2;           // layer
    const int ca   = 4 * w + (l & 3);  // cell
    const int srcl = (l & 3) * 16;     // shfl source lane (D-lane of kg=l&3)
    float cst = 0.f;                   // cell state for this (cell,layer)

    if (tid < 384) ((float*)S)[tid] = 0.f;   // zero both slots + pad
    __syncthreads();

    const char* Sb  = (const char*)S;
    const int  bofs = (lj == 0) ? (kg * 16) : 384;   // pad for inactive lanes
    const f32x4 z = {0.f, 0.f, 0.f, 0.f};

#pragma unroll 1
    for (int p = 0; p <= T_STEPS + 1; ++p) {
        const int so = ((p + 1) & 1) * 768;        // read-slot byte offset
        const char* Bp = Sb + (bofs + so);
        f16x8 b0 = *(const f16x8*)(Bp + 0);        // h0 lo
        f16x8 b1 = *(const f16x8*)(Bp + 64);       // h0 hi
        f16x8 b2 = *(const f16x8*)(Bp + 128);      // h1 lo
        f16x8 b3 = *(const f16x8*)(Bp + 192);      // h1 hi
        f16x8 b4 = *(const f16x8*)(Bp + 256);      // h2 lo
        f16x8 b5 = *(const f16x8*)(Bp + 320);      // h2 hi

        // L0 C-operand: bias + x-term (computed during LDS latency)
        const int px = (p < T_STEPS) ? p : (T_STEPS - 1);
        float2 xt = *(const float2*)&xs[2 * px];
        f32x4 c0;
#pragma unroll
        for (int r = 0; r < 4; ++r)
            c0[r] = cb0[r] + wxv[2 * r] * xt.x + wxv[2 * r + 1] * xt.y;

        // 10 MFMAs; biases ride in C; split accumulators for latency
        f32x4 g0 = MFMA(A00, b0, c0);  g0 = MFMA(A01, b1, g0);
        f32x4 ga = MFMA(A10, b0, cb1); ga = MFMA(A11, b1, ga);
        f32x4 gb = MFMA(A12, b2, z);   gb = MFMA(A13, b3, gb);
        f32x4 g1 = ga + gb;
        f32x4 gc = MFMA(A20, b2, cb2); gc = MFMA(A21, b3, gc);
        f32x4 gd = MFMA(A22, b4, z);   gd = MFMA(A23, b5, gd);
        f32x4 g2 = gc + gd;

        // intra-wave redistribution: lane t<12 pulls layer (t>>2)'s f32x4
        // from D-lane srcl = (t&3)*16. 12 shfls, no barrier.
        float u0 = __shfl(g0[0], srcl), u1 = __shfl(g0[1], srcl);
        float u2 = __shfl(g0[2], srcl), u3 = __shfl(g0[3], srcl);
        float v0 = __shfl(g1[0], srcl), v1 = __shfl(g1[1], srcl);
        float v2 = __shfl(g1[2], srcl), v3 = __shfl(g1[3], srcl);
        float t0 = __shfl(g2[0], srcl), t1 = __shfl(g2[1], srcl);
        float t2 = __shfl(g2[2], srcl), t3 = __shfl(g2[3], srcl);
        float pi = (lam == 0) ? u0 : (lam == 1) ? v0 : t0;
        float pf = (lam == 0) ? u1 : (lam == 1) ? v1 : t1;
        float pg = (lam == 0) ? u2 : (lam == 1) ? v2 : t2;
        float po = (lam == 0) ? u3 : (lam == 1) ? v3 : t3;

        // cell update (1 per lane; lanes >=12 discarded)
        float i_ = sig_f(pi), f_ = sig_f(pf);
        float g_ = tanh_f(pg), o_ = sig_f(po);
        float cn = f_ * cst + i_ * g_;
        float hh = o_ * tanh_f(cn);
        const bool vact = (l < 12) && (p >= lam) && (p < T_STEPS + lam);
        if (vact) {
            cst = cn;
            S[p & 1][lam * H + ca] = (_Float16)hh;
            if (lam == 2 && p == T_STEPS + 1) h2f[ca] = hh;   // final h2
        }
        __syncthreads();
    }

    // ---- fused projection: out[b,:] = h2_last @ Wout^T + bout ----
    if (tid < 11) {
        float acc = bout[tid];
#pragma unroll
        for (int jj = 0; jj < H; ++jj)
            acc += Wout[tid * H + jj] * h2f[jj];
        out[b * 11 + tid] = acc;
    }
}

extern "C" void kernel_launch(void* const* d_in, const int* in_sizes, int n_in,
                              void* d_out, int out_size, void* d_ws, size_t ws_size,
                              hipStream_t stream) {
    const float* x    = (const float*)d_in[0];
    const float* Wih0 = (const float*)d_in[1];
    const float* Whh0 = (const float*)d_in[2];
    const float* bih0 = (const float*)d_in[3];
    const float* bhh0 = (const float*)d_in[4];
    const float* Wih1 = (const float*)d_in[5];
    const float* Whh1 = (const float*)d_in[6];
    const float* bih1 = (const float*)d_in[7];
    const float* bhh1 = (const float*)d_in[8];
    const float* Wih2 = (const float*)d_in[9];
    const float* Whh2 = (const float*)d_in[10];
    const float* bih2 = (const float*)d_in[11];
    const float* bhh2 = (const float*)d_in[12];
    const float* Wout = (const float*)d_in[13];
    const float* bout = (const float*)d_in[14];
    float* out = (float*)d_out;

    lstm3_r18<<<256, 1024, 0, stream>>>(x,
        Wih0, Whh0, bih0, bhh0,
        Wih1, Whh1, bih1, bhh1,
        Wih2, Whh2, bih2, bhh2,
        Wout, bout, out);
}